// Round 4
// baseline (97.518 us; speedup 1.0000x reference)
//
#include <hip/hip_runtime.h>

typedef __bf16 bf16x8 __attribute__((ext_vector_type(8)));
typedef float f32x16 __attribute__((ext_vector_type(16)));

constexpr int kB = 2048, kF = 1024, kP = 64, kK = 64;

// out[b,f] = max_p dot(x[b,:], ww[f,p,:]) * scale[f] + bias[f]
// Single fused kernel. MFMA 32x32x16 bf16, M=p (max-reduced in regs), N=b.
// Per block: 8 f (2/wave, A-frags stationary in 64 VGPR), 512 b.
// x staged fp32->bf16 frag-order into LDS once; ww staged through a 16 KB
// bounce buffer in 4 rounds straight into A-regs. LDS peak 80 KB -> 2 blk/CU.
//
// Frag chunk layouts (16 B chunks of 8 bf16):
//  s_x  byte = bt*4096 + ks*1024 + half*512 + b31*16   (bt=0..15: 32 b-rows)
//  s_ww byte = fl2*8192 + ks*2048 + half*1024 + mt*512 + p31*16 (fl2=0..1)
__global__ __launch_bounds__(256, 2)
void affine_max_fused(const float* __restrict__ x, const float* __restrict__ ww,
                      const float* __restrict__ scale, const float* __restrict__ bias,
                      float* __restrict__ out) {
  __shared__ __align__(16) char s_x[64 * 1024];   // x frags; reused as s_out after
  __shared__ __align__(16) char s_ww[16 * 1024];  // ww bounce (2 f per round)

  const int tid = threadIdx.x, bx = blockIdx.x;
  // XCD i = bx&7 owns fchunks [16i,16i+16) -> 2 MB ww fp32, L2-resident.
  const int fchunk = (bx & 7) * 16 + ((bx >> 3) & 15);  // 0..127
  const int bgroup = bx >> 7;                           // 0..3
  const int f0 = fchunk * 8;
  const int b0 = bgroup * 512;

  const int wv = tid >> 6, lane = tid & 63, l31 = lane & 31, half = lane >> 5;

  // ---- stage x: 512 rows x 64 k, fp32 coalesced -> bf16 frag chunks ----
#pragma unroll
  for (int it = 0; it < 4; ++it) {
    const int g = it * 256 + tid;
    const int r = g >> 1, h = g & 1;              // row, k-half (32 floats)
    const float* src = x + ((size_t)(b0 + r) * kK + h * 32);
    float4 v[8];
#pragma unroll
    for (int j = 0; j < 8; ++j) v[j] = reinterpret_cast<const float4*>(src)[j];
    const int bt = r >> 5, b31 = r & 31;
#pragma unroll
    for (int q = 0; q < 2; ++q)
#pragma unroll
      for (int hf = 0; hf < 2; ++hf) {
        const float4 a = v[q * 4 + hf * 2], b = v[q * 4 + hf * 2 + 1];
        bf16x8 hh;
        hh[0] = (__bf16)a.x; hh[1] = (__bf16)a.y; hh[2] = (__bf16)a.z; hh[3] = (__bf16)a.w;
        hh[4] = (__bf16)b.x; hh[5] = (__bf16)b.y; hh[6] = (__bf16)b.z; hh[7] = (__bf16)b.w;
        *reinterpret_cast<bf16x8*>(s_x + bt * 4096 + (h * 2 + q) * 1024 +
                                   hf * 512 + b31 * 16) = hh;
      }
  }

  // ---- ww rounds: 2 f/round through bounce buffer -> stationary A-regs ----
  bf16x8 afr[2][2][4];
#pragma unroll 1
  for (int rd = 0; rd < 4; ++rd) {
    const int fl2 = tid >> 7, rem = tid & 127, p = rem >> 1, h = rem & 1;
    const float* src = ww + ((size_t)(f0 + rd * 2 + fl2) * (kP * kK) + p * kK + h * 32);
    float4 v[8];
#pragma unroll
    for (int j = 0; j < 8; ++j) v[j] = reinterpret_cast<const float4*>(src)[j];
    __syncthreads();  // previous round's afr reads (and x writes) done
    const int mt = p >> 5, p31 = p & 31;
#pragma unroll
    for (int q = 0; q < 2; ++q)
#pragma unroll
      for (int hf = 0; hf < 2; ++hf) {
        const float4 a = v[q * 4 + hf * 2], b = v[q * 4 + hf * 2 + 1];
        bf16x8 hh;
        hh[0] = (__bf16)a.x; hh[1] = (__bf16)a.y; hh[2] = (__bf16)a.z; hh[3] = (__bf16)a.w;
        hh[4] = (__bf16)b.x; hh[5] = (__bf16)b.y; hh[6] = (__bf16)b.z; hh[7] = (__bf16)b.w;
        *reinterpret_cast<bf16x8*>(s_ww + fl2 * 8192 + (h * 2 + q) * 2048 +
                                   hf * 1024 + mt * 512 + p31 * 16) = hh;
      }
    __syncthreads();
    if (wv == rd) {
#pragma unroll
      for (int fi = 0; fi < 2; ++fi)
#pragma unroll
        for (int m2 = 0; m2 < 2; ++m2)
#pragma unroll
          for (int ks = 0; ks < 4; ++ks)
            afr[fi][m2][ks] = *reinterpret_cast<const bf16x8*>(
                s_ww + fi * 8192 + ks * 2048 + half * 1024 + m2 * 512 + l31 * 16);
    }
  }
  __syncthreads();  // x frags + all afr ready

  // ---- main loop: 16 b-tiles, reg double-buffered B-frags, no barriers ----
  const char* xb = s_x + half * 512 + l31 * 16;
  auto loadB = [&](int t, bf16x8 (&dst)[4]) {
#pragma unroll
    for (int ks = 0; ks < 4; ++ks)
      dst[ks] = *reinterpret_cast<const bf16x8*>(xb + t * 4096 + ks * 1024);
  };
  float vres[16][2];
  auto compute = [&](int t, bf16x8 (&bfr)[4]) {
    f32x16 acc[2][2] = {};
#pragma unroll
    for (int ks = 0; ks < 4; ++ks)
#pragma unroll
      for (int fi = 0; fi < 2; ++fi)
#pragma unroll
        for (int mt = 0; mt < 2; ++mt)
          acc[fi][mt] = __builtin_amdgcn_mfma_f32_32x32x16_bf16(
              afr[fi][mt][ks], bfr[ks], acc[fi][mt], 0, 0, 0);
#pragma unroll
    for (int fi = 0; fi < 2; ++fi) {
      float a[16];
#pragma unroll
      for (int i = 0; i < 16; ++i) a[i] = fmaxf(acc[fi][0][i], acc[fi][1][i]);
#pragma unroll
      for (int s = 8; s >= 1; s >>= 1)
#pragma unroll
        for (int i = 0; i < s; ++i) a[i] = fmaxf(a[i], a[i + s]);
      vres[t][fi] = fmaxf(a[0], __shfl_xor(a[0], 32));
    }
  };

  bf16x8 bA[4], bB[4];
  loadB(0, bA);
#pragma unroll 1
  for (int t = 0; t < 14; t += 2) {
    loadB(t + 1, bB);
    compute(t, bA);
    loadB(t + 2, bA);
    compute(t + 1, bB);
  }
  loadB(15, bB);
  compute(14, bA);
  compute(15, bB);

  __syncthreads();  // all s_x reads done -> safe to overlay s_out

  // ---- transpose maxima through LDS (stride 10 -> 2-way banks = free) ----
  float* s_out = reinterpret_cast<float*>(s_x);  // [512][10]
  if (lane < 32) {
#pragma unroll
    for (int t = 0; t < 16; ++t)
      *reinterpret_cast<float2*>(s_out + (size_t)(t * 32 + l31) * 10 + wv * 2) =
          float2{vres[t][0], vres[t][1]};
  }
  __syncthreads();

  // ---- epilogue: affine + coalesced float4 stores ----
  const int c4 = (tid & 1) * 4;
  const float4 scl = *reinterpret_cast<const float4*>(scale + f0 + c4);
  const float4 bia = *reinterpret_cast<const float4*>(bias + f0 + c4);
#pragma unroll
  for (int i = 0; i < 4; ++i) {
    const int row = i * 128 + (tid >> 1);
    const float2 u0 = *reinterpret_cast<const float2*>(&s_out[row * 10 + c4]);
    const float2 u1 = *reinterpret_cast<const float2*>(&s_out[row * 10 + c4 + 2]);
    float4 r;
    r.x = u0.x * scl.x + bia.x;
    r.y = u0.y * scl.y + bia.y;
    r.z = u1.x * scl.z + bia.z;
    r.w = u1.y * scl.w + bia.w;
    *reinterpret_cast<float4*>(out + (size_t)(b0 + row) * kF + f0 + c4) = r;
  }
}

extern "C" void kernel_launch(void* const* d_in, const int* in_sizes, int n_in,
                              void* d_out, int out_size, void* d_ws, size_t ws_size,
                              hipStream_t stream) {
  const float* x = (const float*)d_in[0];
  const float* ww = (const float*)d_in[1];
  const float* scale = (const float*)d_in[2];
  const float* bias = (const float*)d_in[3];
  float* out = (float*)d_out;
  hipLaunchKernelGGL(affine_max_fused, dim3(512), dim3(256), 0, stream,
                     x, ww, scale, bias, out);
}